// Round 7
// baseline (395.182 us; speedup 1.0000x reference)
//
#include <hip/hip_runtime.h>
#include <hip/hip_bf16.h>
#include <stdint.h>

#define NN 50000
#define NE 800000
#define D 128
#define KH 3
#define SCAN_B ((NN + 255) / 256) // 196

typedef __attribute__((ext_vector_type(8))) __bf16 bf16x8;
typedef __attribute__((ext_vector_type(4))) float f32x4;

__device__ __forceinline__ uint16_t bf16_rne(float f) {
  uint32_t u = __builtin_bit_cast(uint32_t, f);
  u = (u + 0x7fffu + ((u >> 16) & 1u)) >> 16;
  return (uint16_t)u;
}
__device__ __forceinline__ uint32_t bf16_pack(float lo, float hi) {
  return ((uint32_t)bf16_rne(hi) << 16) | (uint32_t)bf16_rne(lo);
}

// async global->LDS, 16B per lane; LDS dest is wave-uniform base + lane*16
#define GLDS16(gp, lp)                                                         \
  __builtin_amdgcn_global_load_lds(                                            \
      (__attribute__((address_space(1))) void*)(gp),                           \
      (__attribute__((address_space(3))) void*)(lp), 16, 0, 0)

__global__ void k_deg(const int* __restrict__ row, int* __restrict__ deg) {
  int e = blockIdx.x * 256 + threadIdx.x;
  if (e < NE) atomicAdd(&deg[row[e]], 1);
}

// fused: dinv + per-block degree sums
__global__ void k_dinv_bsum(const int* __restrict__ deg, float* __restrict__ dinv,
                            int* __restrict__ bsum) {
  __shared__ int s[256];
  int t = threadIdx.x;
  int i = blockIdx.x * 256 + t;
  int d = (i < NN) ? deg[i] : 0;
  if (i < NN) dinv[i] = (d > 0) ? rsqrtf((float)d) : 0.0f;
  s[t] = d;
  __syncthreads();
  for (int off = 128; off > 0; off >>= 1) {
    if (t < off) s[t] += s[t + off];
    __syncthreads();
  }
  if (t == 0) bsum[blockIdx.x] = s[0];
}

// rp/cur writer; block offset computed in-block from bsum
__global__ void k_rpwrite(const int* __restrict__ deg, const int* __restrict__ bsum,
                          int* __restrict__ rp, int* __restrict__ cur) {
  __shared__ int s[256];
  __shared__ int sboff;
  int t = threadIdx.x;
  int b = blockIdx.x;
  int pv = (t < b) ? bsum[t] : 0; // b < SCAN_B <= 256
  s[t] = pv;
  __syncthreads();
  for (int off = 128; off > 0; off >>= 1) {
    if (t < off) s[t] += s[t + off];
    __syncthreads();
  }
  if (t == 0) sboff = s[0];
  __syncthreads();
  int i = b * 256 + t;
  int v = (i < NN) ? deg[i] : 0;
  s[t] = v;
  __syncthreads();
  for (int off = 1; off < 256; off <<= 1) {
    int u = (t >= off) ? s[t - off] : 0;
    __syncthreads();
    s[t] += u;
    __syncthreads();
  }
  if (i < NN) {
    int r = sboff + s[t] - v;
    rp[i] = r;
    cur[i] = r;
  }
  if (i == 0) rp[NN] = NE;
}

__global__ void k_scatter(const int* __restrict__ row, const int* __restrict__ col,
                          const float* __restrict__ dinv, int* __restrict__ cur,
                          int2* __restrict__ csr) {
  int e = blockIdx.x * 256 + threadIdx.x;
  if (e < NE) {
    int r = row[e], c = col[e];
    int pos = atomicAdd(&cur[r], 1);
    csr[pos] = make_int2(c, __float_as_int(dinv[r] * dinv[c]));
  }
}

// fused hop0-convert (8 elems/thread) + weight-prep.
#define XB 6250
__global__ void k_prep_c(const float* __restrict__ x, const float* __restrict__ W,
                         const float* __restrict__ params, uint16_t* __restrict__ dst,
                         uint16_t* __restrict__ wb) {
  int b = blockIdx.x, t = threadIdx.x;
  if (b < XB) {
    int base = (b * 256 + t) * 8; // elem idx in dst
    int n = base >> 8, c0 = base & 255;
    int j = c0 >> 7, dd = c0 & 127;
    const float* xp = x + (size_t)j * NN * D + (size_t)n * D + dd;
    float4 f0 = *(const float4*)xp;
    float4 f1 = *(const float4*)(xp + 4);
    uint4 o;
    o.x = bf16_pack(f0.x, f0.y);
    o.y = bf16_pack(f0.z, f0.w);
    o.z = bf16_pack(f1.x, f1.y);
    o.w = bf16_pack(f1.z, f1.w);
    *(uint4*)(dst + base) = o;
  } else {
    int idx = (b - XB) * 256 + t; // [0, 256*1024)
    int c = idx >> 10, k = idx & 1023;
    int i = c >> 7, f = c & 127, m = k >> 8, j = (k >> 7) & 1, dd = k & 127;
    float p = params[(i * 2 + j) * 4 + m];
    float w = W[((i * 2 + j) * 128 + dd) * 128 + f];
    wb[idx] = bf16_rne(p * w);
  }
}

// fallback variants
__global__ void k_wbig_f(const float* __restrict__ W, const float* __restrict__ params,
                         uint16_t* __restrict__ wb) {
  int idx = blockIdx.x * 256 + threadIdx.x;
  if (idx >= 2 * 256 * 512) return;
  int j = idx >> 17, c = (idx >> 9) & 255, k = idx & 511;
  int i = c >> 7, f = c & 127, m = k >> 7, dd = k & 127;
  float p = params[(i * 2 + j) * 4 + m];
  float w = W[((i * 2 + j) * 128 + dd) * 128 + f];
  wb[idx] = bf16_rne(p * w);
}

__global__ void k_x2h_f(const float* __restrict__ xj, uint16_t* __restrict__ dst) {
  int idx = blockIdx.x * 256 + threadIdx.x;
  if (idx < NN * D) dst[idx] = bf16_rne(xj[idx]);
}

// ---- SpMM: dst = A_norm @ src ----
// One wave per row; HALF-WAVE per edge: 32 lanes cover the row (NDW dwords =
// NCH*8 B per lane), halves take even/odd edges. Uniform clamped batches of
// 16 edges -> 8 dwordx{NDW} gathers per lane per batch, ONE vmcnt wait for a
// typical deg<=16 row. CSR records for BOTH halves are loaded wave-uniformly
// (s_load) and selected per-half with cndmask -- round 5's regression came
// from half-divergent csr[] vector loads; this keeps CSR on the scalar pipe.
// Padded slots clamp to edge e-1 (same row as a real load -> L1-hot) with
// val=0. Final cross-half combine: __shfl_xor(...,32).
template <int NCH>
__global__ void k_spmm(const int* __restrict__ rp, const int2* __restrict__ csr,
                       const uint16_t* __restrict__ src, uint16_t* __restrict__ dst) {
  constexpr int STRIDE = NCH * 128; // elems per row
  constexpr int NDW = NCH * 2;      // dwords per lane (half-wave row coverage)
  typedef uint32_t gvec __attribute__((ext_vector_type(NDW)));
  const int lane = threadIdx.x & 63;
  const int wid = threadIdx.x >> 6;
  const int r = blockIdx.x * 4 + wid;
  if (r >= NN) return;
  const int s = __builtin_amdgcn_readfirstlane(rp[r]);
  const int e = __builtin_amdgcn_readfirstlane(rp[r + 1]);
  const int half = lane >> 5;
  const int lo = (lane & 31) * 2 * NDW; // elem offset within row

  float a[2 * NDW] = {};
  for (int i = s; i < e; i += 16) {
    float val[8];
    gvec g[8];
#pragma unroll
    for (int u = 0; u < 8; ++u) {
      int i0 = i + 2 * u;
      int i1 = i0 + 1;
      int2 c0 = csr[i0 < e ? i0 : e - 1]; // uniform -> s_load
      int2 c1 = csr[i1 < e ? i1 : e - 1]; // uniform -> s_load
      int col = half ? c1.x : c0.x;       // per-half select (cndmask)
      int vb = half ? c1.y : c0.y;
      if (i0 + half >= e) vb = 0; // val = 0 for padded slots
      val[u] = __int_as_float(vb);
      g[u] = *(const gvec*)(src + (size_t)col * STRIDE + lo);
    }
#pragma unroll
    for (int u = 0; u < 8; ++u) {
      float v = val[u];
#pragma unroll
      for (int q = 0; q < NDW; ++q) {
        a[2 * q] = fmaf(v, __builtin_bit_cast(float, g[u][q] << 16), a[2 * q]);
        a[2 * q + 1] =
            fmaf(v, __builtin_bit_cast(float, g[u][q] & 0xffff0000u), a[2 * q + 1]);
      }
    }
  }
  // combine even/odd-edge partial sums across halves
#pragma unroll
  for (int q = 0; q < 2 * NDW; ++q) a[q] += __shfl_xor(a[q], 32);
  if (half == 0) {
    gvec o;
#pragma unroll
    for (int q = 0; q < NDW; ++q) o[q] = bf16_pack(a[2 * q], a[2 * q + 1]);
    *(gvec*)(dst + (size_t)r * STRIDE + lo) = o;
  }
}

// ---- GEMM: out[i*NN+n][f] (+)= sum_k A[n][k] * wb[i*128+f][k] ----
// BK=64: 16KB As + 16KB Bs, 16 barriers, 8 GLDS16/thread in flight.
// XOR-swizzle 16B-chunk index by (row&7) on the GLOBAL source.
template <int KTOT, int HOPW, int ACCUM>
__global__ __launch_bounds__(256) void k_gemm(
    const uint16_t* __restrict__ h0, const uint16_t* __restrict__ h1,
    const uint16_t* __restrict__ h2, const uint16_t* __restrict__ h3,
    const uint16_t* __restrict__ wb, float* __restrict__ out) {
  __shared__ __align__(16) uint16_t As[128 * 64];
  __shared__ __align__(16) uint16_t Bs[128 * 64];
  const uint16_t* hops[4] = {h0, h1, h2, h3};
  int t = threadIdx.x;
  int lane = t & 63, wid = t >> 6;
  int wm = wid >> 1, wn = wid & 1;
  int m0 = blockIdx.x * 128;
  int c0 = blockIdx.y * 128;
  int rl = lane & 15, q = lane >> 4;
  f32x4 acc[4][4] = {};
#pragma unroll
  for (int hop = 0; hop < KTOT / HOPW; ++hop) {
    const uint16_t* hm = hops[hop];
#pragma unroll
    for (int kin = 0; kin < HOPW; kin += 64) {
      int k0 = hop * HOPW + kin;
#pragma unroll
      for (int rr = 0; rr < 4; ++rr) { // stage A: 1024 chunks of 16B
        int c = rr * 256 + t;
        int row = c >> 3, kcL = c & 7;
        int kcG = kcL ^ (row & 7); // swizzle on global source
        int gr = m0 + row;
        gr = gr < NN ? gr : NN - 1; // clamp (dup row harmless, store guarded)
        GLDS16(hm + (size_t)gr * HOPW + kin + kcG * 8, &As[c * 8]);
      }
#pragma unroll
      for (int rr = 0; rr < 4; ++rr) { // stage B
        int c = rr * 256 + t;
        int cc = c >> 3, kcL = c & 7;
        int kcG = kcL ^ (cc & 7);
        GLDS16(wb + (size_t)(c0 + cc) * KTOT + k0 + kcG * 8, &Bs[c * 8]);
      }
      __syncthreads();
#pragma unroll
      for (int kq2 = 0; kq2 < 2; ++kq2) { // two K=32 halves of BK=64
        int w = kq2 * 4 + q;              // wanted 16B chunk 0..7
        bf16x8 af[4], bq[4];
#pragma unroll
        for (int f = 0; f < 4; ++f) {
          int row = wm * 64 + f * 16 + rl;
          af[f] = *(const bf16x8*)(&As[row * 64 + (w ^ (row & 7)) * 8]);
          int col = wn * 64 + f * 16 + rl;
          bq[f] = *(const bf16x8*)(&Bs[col * 64 + (w ^ (col & 7)) * 8]);
        }
#pragma unroll
        for (int fm = 0; fm < 4; ++fm)
#pragma unroll
          for (int fn = 0; fn < 4; ++fn)
            acc[fm][fn] = __builtin_amdgcn_mfma_f32_16x16x32_bf16(af[fm], bq[fn],
                                                                  acc[fm][fn], 0, 0, 0);
      }
      __syncthreads();
    }
  }
  int iOut = blockIdx.y;
#pragma unroll
  for (int fm = 0; fm < 4; ++fm) {
#pragma unroll
    for (int r = 0; r < 4; ++r) {
      int rowg = m0 + wm * 64 + fm * 16 + q * 4 + r;
      if (rowg >= NN) continue;
      float* op = out + ((size_t)iOut * NN + rowg) * D;
#pragma unroll
      for (int fn = 0; fn < 4; ++fn) {
        int colg = wn * 64 + fn * 16 + rl;
        if (ACCUM)
          op[colg] += acc[fm][fn][r];
        else
          op[colg] = acc[fm][fn][r];
      }
    }
  }
}

extern "C" void kernel_launch(void* const* d_in, const int* in_sizes, int n_in,
                              void* d_out, int out_size, void* d_ws, size_t ws_size,
                              hipStream_t stream) {
  (void)in_sizes; (void)n_in; (void)out_size;
  const float* x = (const float*)d_in[0];      // [2, N, 128]
  const int* ei = (const int*)d_in[1];         // [2, E]
  const float* W = (const float*)d_in[2];      // [2, 2, 128, 128]
  const float* params = (const float*)d_in[3]; // [2, 2, 4]
  float* out = (float*)d_out;                  // [2, N, 128]
  char* ws = (char*)d_ws;

  size_t off = 0;
  auto take = [&](size_t bytes) {
    char* p = ws + off;
    off = (off + bytes + 255) & ~(size_t)255;
    return p;
  };
  int* deg = (int*)take((size_t)NN * 4);
  float* dinv = (float*)take((size_t)NN * 4);
  int* rp = (int*)take((size_t)(NN + 1) * 4);
  int* cur = (int*)take((size_t)NN * 4);
  int* bsum = (int*)take(256 * 4);
  int2* csr = (int2*)take((size_t)NE * 8);
  uint16_t* wb = (uint16_t*)take((size_t)256 * 1024 * 2); // 512 KB
  size_t fixed = off;

  hipMemsetAsync(deg, 0, (size_t)NN * 4, stream);
  k_deg<<<(NE + 255) / 256, 256, 0, stream>>>(ei, deg);
  k_dinv_bsum<<<SCAN_B, 256, 0, stream>>>(deg, dinv, bsum);
  k_rpwrite<<<SCAN_B, 256, 0, stream>>>(deg, bsum, rp, cur);
  k_scatter<<<(NE + 255) / 256, 256, 0, stream>>>(ei, ei + NE, dinv, cur, csr);

  size_t hopC = (size_t)NN * 256 * 2; // 25.6 MB per hop, combined channels
  size_t needC = fixed + 4 * hopC + 1024;

  if (ws_size >= needC) {
    // ---- fused-channel path: 3 spmm + 1 GEMM (K=1024) ----
    uint16_t* hop[4];
    for (int m = 0; m < 4; ++m) hop[m] = (uint16_t*)take(hopC);
    k_prep_c<<<XB + 1024, 256, 0, stream>>>(x, W, params, hop[0], wb);
    for (int m = 1; m <= KH; ++m)
      k_spmm<2><<<(NN + 3) / 4, 256, 0, stream>>>(rp, csr, hop[m - 1], hop[m]);
    dim3 grid((NN + 127) / 128, 2);
    k_gemm<1024, 256, 0><<<grid, 256, 0, stream>>>(hop[0], hop[1], hop[2], hop[3],
                                                   wb, out);
  } else {
    // ---- fallback: per-channel hops, 2 GEMMs ----
    size_t hopF = (size_t)NN * 128 * 2;
    uint16_t* hop[4];
    for (int m = 0; m < 4; ++m) hop[m] = (uint16_t*)take(hopF);
    k_wbig_f<<<(2 * 256 * 512 + 255) / 256, 256, 0, stream>>>(W, params, wb);
    for (int j = 0; j < 2; ++j) {
      k_x2h_f<<<(NN * D + 255) / 256, 256, 0, stream>>>(x + (size_t)j * NN * D, hop[0]);
      for (int m = 1; m <= KH; ++m)
        k_spmm<1><<<(NN + 3) / 4, 256, 0, stream>>>(rp, csr, hop[m - 1], hop[m]);
      dim3 grid((NN + 127) / 128, 2);
      if (j == 0)
        k_gemm<512, 128, 0><<<grid, 256, 0, stream>>>(hop[0], hop[1], hop[2], hop[3],
                                                      wb, out);
      else
        k_gemm<512, 128, 1><<<grid, 256, 0, stream>>>(hop[0], hop[1], hop[2], hop[3],
                                                      wb + 256 * 512, out);
    }
  }
}